// Round 4
// baseline (2273.208 us; speedup 1.0000x reference)
//
#include <hip/hip_runtime.h>

#define BN_SCALE 0.9999950000374997f  // 1/sqrt(1+1e-5)

// ---------------- sqnorm: sq[b,n] = sum_c X[b,c,n]^2 ----------------
__global__ void sqnorm_kernel(const float* __restrict__ X, int xStrideB,
                              int C, int Np, float* __restrict__ sq) {
  int b = blockIdx.y;
  int n = blockIdx.x * blockDim.x + threadIdx.x;
  if (n >= Np) return;
  const float* p = X + (long)b * xStrideB + n;
  float s = 0.f;
  for (int c = 0; c < C; ++c) { float v = p[(long)c * Np]; s = fmaf(v, v, s); }
  sq[(long)b * Np + n] = s;
}

// ---------------- knn4: 4 queries per block; dot phase shared, per-wave top-k extract ----------------
__global__ void knn4_kernel(const float* __restrict__ Q, int qStrideB,
                            const float* __restrict__ Xc, int cStrideB,
                            const float* __restrict__ sqQ, const float* __restrict__ sqC,
                            int C, int M, int N, int k, int* __restrict__ idxOut) {
  __shared__ float qv[4][256];
  __shared__ float negd[4][2048];
  int b = blockIdx.y, q0 = blockIdx.x * 4, tid = threadIdx.x;
  for (int e = tid; e < 4 * C; e += 256) {
    int qq = e / C, c = e % C;
    qv[qq][c] = Q[(long)b * qStrideB + (long)c * M + (q0 + qq)];
  }
  __syncthreads();
  float s0 = sqQ[(long)b * M + q0 + 0];
  float s1 = sqQ[(long)b * M + q0 + 1];
  float s2 = sqQ[(long)b * M + q0 + 2];
  float s3 = sqQ[(long)b * M + q0 + 3];
  const float* cb = Xc + (long)b * cStrideB;
  const float* sc = sqC + (long)b * N;
  for (int m = tid; m < N; m += 256) {
    float d0 = 0.f, d1 = 0.f, d2 = 0.f, d3 = 0.f;
    for (int c = 0; c < C; ++c) {
      float xv = cb[(long)c * N + m];
      d0 = fmaf(qv[0][c], xv, d0);
      d1 = fmaf(qv[1][c], xv, d1);
      d2 = fmaf(qv[2][c], xv, d2);
      d3 = fmaf(qv[3][c], xv, d3);
    }
    float scm = sc[m];
    negd[0][m] = 2.f * d0 - s0 - scm;
    negd[1][m] = 2.f * d1 - s1 - scm;
    negd[2][m] = 2.f * d2 - s2 - scm;
    negd[3][m] = 2.f * d3 - s3 - scm;
  }
  __syncthreads();
  int lane = tid & 63, w = tid >> 6;
  float* row = negd[w];
  int* outp = idxOut + ((long)b * M + (q0 + w)) * k;
  for (int kk = 0; kk < k; ++kk) {
    float best = -INFINITY; int bi = N;
    for (int m = lane; m < N; m += 64) {
      float v = row[m];
      if (v > best) { best = v; bi = m; }
    }
    for (int off = 32; off > 0; off >>= 1) {
      float ov = __shfl_xor(best, off);
      int   oi = __shfl_xor(bi, off);
      if (ov > best || (ov == best && oi < bi)) { best = ov; bi = oi; }
    }
    if (lane == (bi & 63)) row[bi] = -INFINITY;
    if (lane == 0) outp[kk] = bi;
  }
}

// ---------------- gemmT: outT[b][n][o] = sum_c W[o*ldw+c] * X[b][c][n] ----------------
__global__ void gemmT_kernel(const float* __restrict__ X, int xStrideB, int C, int Np,
                             const float* __restrict__ W, int ldw, int O,
                             float* __restrict__ outT) {
  __shared__ float Wt[16][65];
  __shared__ float Xt[16][65];
  int b = blockIdx.z;
  int n0 = blockIdx.x * 64, o0 = blockIdx.y * 64;
  int tid = threadIdx.x;
  int to = tid % 16, tn = tid / 16;
  float acc[4][4] = {};
  for (int c0 = 0; c0 < C; c0 += 16) {
    for (int e = tid; e < 16 * 64; e += 256) {
      int oo = e / 16, kk = e % 16;
      int c = c0 + kk, o = o0 + oo;
      Wt[kk][oo] = (c < C && o < O) ? W[(long)o * ldw + c] : 0.f;
    }
    for (int e = tid; e < 16 * 64; e += 256) {
      int kk = e / 64, nn = e % 64;
      int c = c0 + kk, n = n0 + nn;
      Xt[kk][nn] = (c < C && n < Np) ? X[(long)b * xStrideB + (long)c * Np + n] : 0.f;
    }
    __syncthreads();
    for (int kk = 0; kk < 16; ++kk) {
      float xv[4], wv[4];
      for (int i = 0; i < 4; ++i) xv[i] = Xt[kk][tn + 16 * i];
      for (int j = 0; j < 4; ++j) wv[j] = Wt[kk][to + 16 * j];
      for (int i = 0; i < 4; ++i)
        for (int j = 0; j < 4; ++j) acc[i][j] = fmaf(xv[i], wv[j], acc[i][j]);
    }
    __syncthreads();
  }
  for (int i = 0; i < 4; ++i) {
    int n = n0 + tn + 16 * i;
    if (n >= Np) continue;
    for (int j = 0; j < 4; ++j) {
      int o = o0 + to + 16 * j;
      if (o < O) outT[((long)b * Np + n) * O + o] = acc[i][j];
    }
  }
}

// ---------------- ecfinish: out[b,o,n] = lrelu(bn(S[n,o]-P[n,o] + max/min_k P[idx[n,k],o])) ----------------
__global__ void ecfinish_kernel(const float* __restrict__ Pt, const float* __restrict__ St,
                                const int* __restrict__ idx, int k, int O, int Np,
                                const float* __restrict__ g, const float* __restrict__ bb,
                                float* __restrict__ outp, long oStrideB) {
  int b = blockIdx.y;
  int n = blockIdx.x * blockDim.y + threadIdx.y;
  int o = threadIdx.x;
  const float* PtB = Pt + (long)b * Np * O;
  const float* StB = St + (long)b * Np * O;
  const int* ip = idx + ((long)b * Np + n) * k;
  float mx = -INFINITY, mn = INFINITY;
  for (int kk = 0; kk < k; ++kk) {
    float v = PtB[(long)ip[kk] * O + o];
    mx = fmaxf(mx, v); mn = fminf(mn, v);
  }
  float ctrP = PtB[(long)n * O + o];
  float ctrS = StB[(long)n * O + o];
  float gs = g[o] * BN_SCALE;
  float m = (gs >= 0.f) ? mx : mn;
  float h = (ctrS - ctrP + m) * gs + bb[o];
  outp[(long)b * oStrideB + (long)o * Np + n] = h >= 0.f ? h : 0.2f * h;
}

// ---------------- gemm_colmax: tile GEMM + lrelu(bn()) + max over n-tile -> partial[b][nt][o] ----------------
__global__ void gemm_colmax_kernel(const float* __restrict__ X, int xStrideB, int C, int Np,
                                   const float* __restrict__ W, int ldw, int O,
                                   const float* __restrict__ g, const float* __restrict__ bb,
                                   float* __restrict__ partial) {
  __shared__ float Wt[16][65];
  __shared__ float Xt[16][65];
  int b = blockIdx.z;
  int n0 = blockIdx.x * 64, o0 = blockIdx.y * 64;
  int tid = threadIdx.x;
  int to = tid % 16, tn = tid / 16;
  float acc[4][4] = {};
  for (int c0 = 0; c0 < C; c0 += 16) {
    for (int e = tid; e < 16 * 64; e += 256) {
      int oo = e / 16, kk = e % 16;
      int c = c0 + kk, o = o0 + oo;
      Wt[kk][oo] = (c < C && o < O) ? W[(long)o * ldw + c] : 0.f;
    }
    for (int e = tid; e < 16 * 64; e += 256) {
      int kk = e / 64, nn = e % 64;
      int c = c0 + kk, n = n0 + nn;
      Xt[kk][nn] = (c < C && n < Np) ? X[(long)b * xStrideB + (long)c * Np + n] : 0.f;
    }
    __syncthreads();
    for (int kk = 0; kk < 16; ++kk) {
      float xv[4], wv[4];
      for (int i = 0; i < 4; ++i) xv[i] = Xt[kk][tn + 16 * i];
      for (int j = 0; j < 4; ++j) wv[j] = Wt[kk][to + 16 * j];
      for (int i = 0; i < 4; ++i)
        for (int j = 0; j < 4; ++j) acc[i][j] = fmaf(xv[i], wv[j], acc[i][j]);
    }
    __syncthreads();
  }
  float vm[4];
  for (int j = 0; j < 4; ++j) {
    int o = o0 + to + 16 * j;
    float gs = g[o] * BN_SCALE, bo = bb[o];
    float m = -INFINITY;
    for (int i = 0; i < 4; ++i) {
      float h = acc[i][j] * gs + bo;
      h = h >= 0.f ? h : 0.2f * h;
      m = fmaxf(m, h);
    }
    vm[j] = m;
  }
  for (int j = 0; j < 4; ++j) Xt[tn][to + 16 * j] = vm[j];
  __syncthreads();
  for (int s = 8; s > 0; s >>= 1) {
    if (tn < s)
      for (int j = 0; j < 4; ++j)
        Xt[tn][to + 16 * j] = fmaxf(Xt[tn][to + 16 * j], Xt[tn + s][to + 16 * j]);
    __syncthreads();
  }
  if (tn == 0)
    for (int j = 0; j < 4; ++j) {
      int o = o0 + to + 16 * j;
      partial[((long)b * gridDim.x + blockIdx.x) * O + o] = Xt[0][to + 16 * j];
    }
}

// ---------------- colmax_finish: out[b][o] = max_t partial[b][t][o] ----------------
__global__ void colmax_finish_kernel(const float* __restrict__ partial, int NT, int O,
                                     float* __restrict__ outp) {
  int b = blockIdx.y;
  int o = blockIdx.x * 256 + threadIdx.x;
  if (o >= O) return;
  float m = -INFINITY;
  for (int t = 0; t < NT; ++t) m = fmaxf(m, partial[((long)b * NT + t) * O + o]);
  outp[(long)b * O + o] = m;
}

// ---------------- FPS: SINGLE WAVE per batch; dist in VGPRs; no barriers ----------------
// N=2048: 64 lanes x 32 contiguous points. Per iter: LDS broadcast of 'last' coords,
// register distance update, 6-step xor-butterfly all-reduce of (best,idx).
__global__ void __launch_bounds__(64) fps_kernel(const float* __restrict__ xyz, int N, int M,
                                                 int* __restrict__ fpsIdx, float* __restrict__ node1) {
  #pragma clang fp contract(off)
  __shared__ float sx[2048], sy[2048], sz[2048];
  __shared__ int fidx[512];
  int b = blockIdx.x, lane = threadIdx.x;
  const float* xb = xyz + (long)b * 3 * N;
  for (int n = lane; n < N; n += 64) {
    sx[n] = xb[n]; sy[n] = xb[N + n]; sz[n] = xb[2 * N + n];
  }
  int base = lane * 32;
  float px[32], py[32], pz[32], dist[32];
  #pragma unroll
  for (int i = 0; i < 32; i += 4) {
    float4 a = *(const float4*)(xb + base + i);
    px[i] = a.x; px[i + 1] = a.y; px[i + 2] = a.z; px[i + 3] = a.w;
    float4 bb4 = *(const float4*)(xb + N + base + i);
    py[i] = bb4.x; py[i + 1] = bb4.y; py[i + 2] = bb4.z; py[i + 3] = bb4.w;
    float4 cc = *(const float4*)(xb + 2 * N + base + i);
    pz[i] = cc.x; pz[i + 1] = cc.y; pz[i + 2] = cc.z; pz[i + 3] = cc.w;
  }
  #pragma unroll
  for (int i = 0; i < 32; ++i) dist[i] = 1e10f;
  int last = 0;
  for (int it = 0; it < M; ++it) {
    if (lane == 0) fidx[it] = last;
    float lx = sx[last], ly = sy[last], lz = sz[last];  // same-address broadcast
    float best = -INFINITY; int bi = N;
    #pragma unroll
    for (int i = 0; i < 32; ++i) {
      float dx = px[i] - lx, dy = py[i] - ly, dz = pz[i] - lz;
      float dx2 = dx * dx, dy2 = dy * dy, dz2 = dz * dz;
      float d = (dx2 + dy2) + dz2;
      float dn = dist[i];
      if (d < dn) dn = d;
      dist[i] = dn;
      if (dn > best) { best = dn; bi = base + i; }  // ascending -> first max kept
    }
    // xor-butterfly all-reduce; ties -> smaller index (lanes ascend in base)
    #pragma unroll
    for (int off = 32; off > 0; off >>= 1) {
      float ov = __shfl_xor(best, off);
      int   oi = __shfl_xor(bi, off);
      if (ov > best || (ov == best && oi < bi)) { best = ov; bi = oi; }
    }
    last = bi;  // all lanes agree
  }
  // flush fpsIdx + node1 from LDS
  for (int e = lane; e < M; e += 64) fpsIdx[(long)b * M + e] = fidx[e];
  for (int e = lane; e < 3 * M; e += 64) {
    int c = e / M, i = e % M;
    int src = fidx[i];
    float v = (c == 0) ? sx[src] : (c == 1) ? sy[src] : sz[src];
    node1[(long)b * 3 * M + e] = v;
  }
}

// ---------------- gather: out[b,c,i] = X[b,c,idx[b,i]] ----------------
__global__ void gather_kernel(const float* __restrict__ X, int xStrideB, int C, int N,
                              const int* __restrict__ idx, int M,
                              float* __restrict__ outp, int oStrideB, int B) {
  long t = (long)blockIdx.x * blockDim.x + threadIdx.x;
  long total = (long)B * C * M;
  if (t >= total) return;
  int i = (int)(t % M);
  int c = (int)((t / M) % C);
  int b = (int)(t / ((long)C * M));
  int src = idx[(long)b * M + i];
  outp[(long)b * oStrideB + (long)c * M + i] = X[(long)b * xStrideB + (long)c * N + src];
}

// ---------------- gathermax: out[b,c,i] = max_k X[b,c,idx[b,i,k]] ----------------
__global__ void gathermax_kernel(const float* __restrict__ X, int xStrideB, int C, int N,
                                 const int* __restrict__ idx, int k, int M,
                                 float* __restrict__ outp, int oStrideB, int B) {
  long t = (long)blockIdx.x * blockDim.x + threadIdx.x;
  long total = (long)B * C * M;
  if (t >= total) return;
  int i = (int)(t % M);
  int c = (int)((t / M) % C);
  int b = (int)(t / ((long)C * M));
  const int* ip = idx + ((long)b * M + i) * k;
  const float* xb = X + (long)b * xStrideB + (long)c * N;
  float best = -INFINITY;
  for (int kk = 0; kk < k; ++kk) best = fmaxf(best, xb[ip[kk]]);
  outp[(long)b * oStrideB + (long)c * M + i] = best;
}

// ---------------- head: v=[vf;vs] -> 3-layer MLP -> logits ----------------
__global__ void head_kernel(const float* __restrict__ vf, const float* __restrict__ vs,
                            const float* __restrict__ Wl1, const float* __restrict__ g6, const float* __restrict__ b6,
                            const float* __restrict__ Wl2, const float* __restrict__ bl2,
                            const float* __restrict__ g7, const float* __restrict__ b7,
                            const float* __restrict__ Wl3, const float* __restrict__ bl3,
                            float* __restrict__ logits) {
  __shared__ float v[2048];
  __shared__ float h1[512];
  __shared__ float h2[256];
  int b = blockIdx.x, tid = threadIdx.x;
  for (int c = tid; c < 1024; c += 256) {
    v[c]        = vf[(long)b * 1024 + c];
    v[1024 + c] = vs[(long)b * 1024 + c];
  }
  __syncthreads();
  for (int o = tid; o < 512; o += 256) {
    const float* wr = Wl1 + (long)o * 2048;
    float s = 0.f;
    for (int c = 0; c < 2048; c += 4) {
      float4 w4 = *(const float4*)(wr + c);
      s = fmaf(w4.x, v[c], s); s = fmaf(w4.y, v[c + 1], s);
      s = fmaf(w4.z, v[c + 2], s); s = fmaf(w4.w, v[c + 3], s);
    }
    float h = s * (g6[o] * BN_SCALE) + b6[o];
    h1[o] = h >= 0.f ? h : 0.2f * h;
  }
  __syncthreads();
  for (int o = tid; o < 256; o += 256) {
    const float* wr = Wl2 + (long)o * 512;
    float s = 0.f;
    for (int c = 0; c < 512; c += 4) {
      float4 w4 = *(const float4*)(wr + c);
      s = fmaf(w4.x, h1[c], s); s = fmaf(w4.y, h1[c + 1], s);
      s = fmaf(w4.z, h1[c + 2], s); s = fmaf(w4.w, h1[c + 3], s);
    }
    s += bl2[o];
    float h = s * (g7[o] * BN_SCALE) + b7[o];
    h2[o] = h >= 0.f ? h : 0.2f * h;
  }
  __syncthreads();
  if (tid < 40) {
    const float* wr = Wl3 + (long)tid * 256;
    float s = 0.f;
    for (int c = 0; c < 256; ++c) s = fmaf(wr[c], h2[c], s);
    logits[(long)b * 40 + tid] = s + bl3[tid];
  }
}

extern "C" void kernel_launch(void* const* d_in, const int* in_sizes, int n_in,
                              void* d_out, int out_size, void* d_ws, size_t ws_size,
                              hipStream_t stream) {
  const float* x   = (const float*)d_in[0];
  const float* W1  = (const float*)d_in[1];
  const float* g1  = (const float*)d_in[2];
  const float* b1  = (const float*)d_in[3];
  const float* W2  = (const float*)d_in[4];
  const float* g2  = (const float*)d_in[5];
  const float* b2  = (const float*)d_in[6];
  const float* W2m = (const float*)d_in[7];
  const float* g2m = (const float*)d_in[8];
  const float* b2m = (const float*)d_in[9];
  const float* W3  = (const float*)d_in[10];
  const float* g3  = (const float*)d_in[11];
  const float* b3  = (const float*)d_in[12];
  const float* W4  = (const float*)d_in[13];
  const float* g4  = (const float*)d_in[14];
  const float* b4  = (const float*)d_in[15];
  const float* W5  = (const float*)d_in[16];
  const float* g5  = (const float*)d_in[17];
  const float* b5  = (const float*)d_in[18];
  const float* Wl1 = (const float*)d_in[19];
  const float* g6  = (const float*)d_in[20];
  const float* b6  = (const float*)d_in[21];
  const float* Wl2 = (const float*)d_in[22];
  const float* bl2 = (const float*)d_in[23];
  const float* g7  = (const float*)d_in[24];
  const float* b7  = (const float*)d_in[25];
  const float* Wl3 = (const float*)d_in[26];
  const float* bl3 = (const float*)d_in[27];
  float* outF = (float*)d_out;

  const int B = 8, N = 2048, K = 20, M = 512, K2 = 10;

  float* ws   = (float*)d_ws;
  float* xt1  = ws;                              // (B,128,N)
  float* xm   = xt1 + (size_t)B * 128 * N;       // (B,256,M)
  float* xc   = xm  + (size_t)B * 256 * M;       // (B,512,M)
  float* Pt   = xc  + (size_t)B * 512 * M;       // (B,N,64)/(B,M,256)
  float* St   = Pt  + (size_t)B * N * 64;
  float* part = St  + (size_t)B * N * 64;        // (B,32,1024)
  float* vf   = part + (size_t)B * 32 * 1024;
  float* vs   = vf  + (size_t)B * 1024;
  float* sqa  = vs  + (size_t)B * 1024;
  float* sqb  = sqa + (size_t)B * N;
  float* sqn  = sqb + (size_t)B * N;
  int*   idxK = (int*)(sqn + (size_t)B * M);
  int*   fpsI = idxK + (size_t)B * N * K;

  float* logits = outF;        // (B,40)
  float* node1  = outF + 320;  // (B,3,M)

  dim3 t256(256);

  // ---- stage 1
  sqnorm_kernel<<<dim3((N + 255) / 256, B), t256, 0, stream>>>(x, 3 * N, 3, N, sqa);
  knn4_kernel<<<dim3(N / 4, B), t256, 0, stream>>>(x, 3 * N, x, 3 * N, sqa, sqa, 3, N, N, K, idxK);
  gemmT_kernel<<<dim3(N / 64, 1, B), t256, 0, stream>>>(x, 3 * N, 3, N, W1,     6, 64, Pt);
  gemmT_kernel<<<dim3(N / 64, 1, B), t256, 0, stream>>>(x, 3 * N, 3, N, W1 + 3, 6, 64, St);
  ecfinish_kernel<<<dim3(N / 4, B), dim3(64, 4), 0, stream>>>(Pt, St, idxK, K, 64, N, g1, b1, xt1, (long)128 * N);

  // FPS
  fps_kernel<<<dim3(B), dim3(64), 0, stream>>>(x, N, M, fpsI, node1);

  // ---- stage 2
  sqnorm_kernel<<<dim3((N + 255) / 256, B), t256, 0, stream>>>(xt1, 128 * N, 64, N, sqb);
  knn4_kernel<<<dim3(N / 4, B), t256, 0, stream>>>(xt1, 128 * N, xt1, 128 * N, sqb, sqb, 64, N, N, K, idxK);
  gemmT_kernel<<<dim3(N / 64, 1, B), t256, 0, stream>>>(xt1, 128 * N, 64, N, W2,      128, 64, Pt);
  gemmT_kernel<<<dim3(N / 64, 1, B), t256, 0, stream>>>(xt1, 128 * N, 64, N, W2 + 64, 128, 64, St);
  ecfinish_kernel<<<dim3(N / 4, B), dim3(64, 4), 0, stream>>>(Pt, St, idxK, K, 64, N, g2, b2,
                                                              xt1 + (size_t)64 * N, (long)128 * N);

  // ---- vf
  gemm_colmax_kernel<<<dim3(N / 64, 1024 / 64, B), t256, 0, stream>>>(xt1, 128 * N, 128, N, W2m, 128, 1024,
                                                                      g2m, b2m, part);
  colmax_finish_kernel<<<dim3(1024 / 256, B), t256, 0, stream>>>(part, N / 64, 1024, vf);

  // ---- nf1 gather
  gather_kernel<<<dim3((B * 128 * M + 255) / 256), t256, 0, stream>>>(xt1, 128 * N, 128, N, fpsI, M, xm, 256 * M, B);

  // ---- aggregate
  sqnorm_kernel<<<dim3((M + 255) / 256, B), t256, 0, stream>>>(node1, 3 * M, 3, M, sqn);
  knn4_kernel<<<dim3(M / 4, B), t256, 0, stream>>>(node1, 3 * M, x, 3 * N, sqn, sqa, 3, M, N, K, idxK);
  gathermax_kernel<<<dim3((B * 128 * M + 255) / 256), t256, 0, stream>>>(xt1, 128 * N, 128, N, idxK, K, M,
                                                                         xm + (size_t)128 * M, 256 * M, B);

  // ---- stage 3
  sqnorm_kernel<<<dim3((M + 255) / 256, B), t256, 0, stream>>>(xm, 256 * M, 256, M, sqb);
  knn4_kernel<<<dim3(M / 4, B), t256, 0, stream>>>(xm, 256 * M, xm, 256 * M, sqb, sqb, 256, M, M, K2, idxK);
  gemmT_kernel<<<dim3(M / 64, 256 / 64, B), t256, 0, stream>>>(xm, 256 * M, 256, M, W3,       512, 256, Pt);
  gemmT_kernel<<<dim3(M / 64, 256 / 64, B), t256, 0, stream>>>(xm, 256 * M, 256, M, W3 + 256, 512, 256, St);
  ecfinish_kernel<<<dim3(M, B), dim3(256, 1), 0, stream>>>(Pt, St, idxK, K2, 256, M, g3, b3, xc, (long)512 * M);

  // ---- stage 4
  sqnorm_kernel<<<dim3((M + 255) / 256, B), t256, 0, stream>>>(xc, 512 * M, 256, M, sqb);
  knn4_kernel<<<dim3(M / 4, B), t256, 0, stream>>>(xc, 512 * M, xc, 512 * M, sqb, sqb, 256, M, M, K2, idxK);
  gemmT_kernel<<<dim3(M / 64, 256 / 64, B), t256, 0, stream>>>(xc, 512 * M, 256, M, W4,       512, 256, Pt);
  gemmT_kernel<<<dim3(M / 64, 256 / 64, B), t256, 0, stream>>>(xc, 512 * M, 256, M, W4 + 256, 512, 256, St);
  ecfinish_kernel<<<dim3(M, B), dim3(256, 1), 0, stream>>>(Pt, St, idxK, K2, 256, M, g4, b4,
                                                           xc + (size_t)256 * M, (long)512 * M);

  // ---- vs
  gemm_colmax_kernel<<<dim3(M / 64, 1024 / 64, B), t256, 0, stream>>>(xc, 512 * M, 512, M, W5, 512, 1024,
                                                                      g5, b5, part);
  colmax_finish_kernel<<<dim3(1024 / 256, B), t256, 0, stream>>>(part, M / 64, 1024, vs);

  // ---- head
  head_kernel<<<dim3(B), t256, 0, stream>>>(vf, vs, Wl1, g6, b6, Wl2, bl2, g7, b7, Wl3, bl3, logits);
}

// Round 5
// 2134.472 us; speedup vs baseline: 1.0650x; 1.0650x over previous
//
#include <hip/hip_runtime.h>

#define BN_SCALE 0.9999950000374997f  // 1/sqrt(1+1e-5)

// ---------------- sqnorm: sq[b,n] = sum_c X[b,c,n]^2 ----------------
__global__ void sqnorm_kernel(const float* __restrict__ X, int xStrideB,
                              int C, int Np, float* __restrict__ sq) {
  int b = blockIdx.y;
  int n = blockIdx.x * blockDim.x + threadIdx.x;
  if (n >= Np) return;
  const float* p = X + (long)b * xStrideB + n;
  float s = 0.f;
  for (int c = 0; c < C; ++c) { float v = p[(long)c * Np]; s = fmaf(v, v, s); }
  sq[(long)b * Np + n] = s;
}

// ---------------- knn4: 4 queries per block; dot phase shared, per-wave top-k extract ----------------
__global__ void knn4_kernel(const float* __restrict__ Q, int qStrideB,
                            const float* __restrict__ Xc, int cStrideB,
                            const float* __restrict__ sqQ, const float* __restrict__ sqC,
                            int C, int M, int N, int k, int* __restrict__ idxOut) {
  __shared__ float qv[4][256];
  __shared__ float negd[4][2048];
  int b = blockIdx.y, q0 = blockIdx.x * 4, tid = threadIdx.x;
  for (int e = tid; e < 4 * C; e += 256) {
    int qq = e / C, c = e % C;
    qv[qq][c] = Q[(long)b * qStrideB + (long)c * M + (q0 + qq)];
  }
  __syncthreads();
  float s0 = sqQ[(long)b * M + q0 + 0];
  float s1 = sqQ[(long)b * M + q0 + 1];
  float s2 = sqQ[(long)b * M + q0 + 2];
  float s3 = sqQ[(long)b * M + q0 + 3];
  const float* cb = Xc + (long)b * cStrideB;
  const float* sc = sqC + (long)b * N;
  for (int m = tid; m < N; m += 256) {
    float d0 = 0.f, d1 = 0.f, d2 = 0.f, d3 = 0.f;
    for (int c = 0; c < C; ++c) {
      float xv = cb[(long)c * N + m];
      d0 = fmaf(qv[0][c], xv, d0);
      d1 = fmaf(qv[1][c], xv, d1);
      d2 = fmaf(qv[2][c], xv, d2);
      d3 = fmaf(qv[3][c], xv, d3);
    }
    float scm = sc[m];
    negd[0][m] = 2.f * d0 - s0 - scm;
    negd[1][m] = 2.f * d1 - s1 - scm;
    negd[2][m] = 2.f * d2 - s2 - scm;
    negd[3][m] = 2.f * d3 - s3 - scm;
  }
  __syncthreads();
  int lane = tid & 63, w = tid >> 6;
  float* row = negd[w];
  int* outp = idxOut + ((long)b * M + (q0 + w)) * k;
  for (int kk = 0; kk < k; ++kk) {
    float best = -INFINITY; int bi = N;
    for (int m = lane; m < N; m += 64) {
      float v = row[m];
      if (v > best) { best = v; bi = m; }
    }
    for (int off = 32; off > 0; off >>= 1) {
      float ov = __shfl_xor(best, off);
      int   oi = __shfl_xor(bi, off);
      if (ov > best || (ov == best && oi < bi)) { best = ov; bi = oi; }
    }
    if (lane == (bi & 63)) row[bi] = -INFINITY;
    if (lane == 0) outp[kk] = bi;
  }
}

// ---------------- gemmT: outT[b][n][o] = sum_c W[o*ldw+c] * X[b][c][n] ----------------
__global__ void gemmT_kernel(const float* __restrict__ X, int xStrideB, int C, int Np,
                             const float* __restrict__ W, int ldw, int O,
                             float* __restrict__ outT) {
  __shared__ float Wt[16][65];
  __shared__ float Xt[16][65];
  int b = blockIdx.z;
  int n0 = blockIdx.x * 64, o0 = blockIdx.y * 64;
  int tid = threadIdx.x;
  int to = tid % 16, tn = tid / 16;
  float acc[4][4] = {};
  for (int c0 = 0; c0 < C; c0 += 16) {
    for (int e = tid; e < 16 * 64; e += 256) {
      int oo = e / 16, kk = e % 16;
      int c = c0 + kk, o = o0 + oo;
      Wt[kk][oo] = (c < C && o < O) ? W[(long)o * ldw + c] : 0.f;
    }
    for (int e = tid; e < 16 * 64; e += 256) {
      int kk = e / 64, nn = e % 64;
      int c = c0 + kk, n = n0 + nn;
      Xt[kk][nn] = (c < C && n < Np) ? X[(long)b * xStrideB + (long)c * Np + n] : 0.f;
    }
    __syncthreads();
    for (int kk = 0; kk < 16; ++kk) {
      float xv[4], wv[4];
      for (int i = 0; i < 4; ++i) xv[i] = Xt[kk][tn + 16 * i];
      for (int j = 0; j < 4; ++j) wv[j] = Wt[kk][to + 16 * j];
      for (int i = 0; i < 4; ++i)
        for (int j = 0; j < 4; ++j) acc[i][j] = fmaf(xv[i], wv[j], acc[i][j]);
    }
    __syncthreads();
  }
  for (int i = 0; i < 4; ++i) {
    int n = n0 + tn + 16 * i;
    if (n >= Np) continue;
    for (int j = 0; j < 4; ++j) {
      int o = o0 + to + 16 * j;
      if (o < O) outT[((long)b * Np + n) * O + o] = acc[i][j];
    }
  }
}

// ---------------- ecfinish: out[b,o,n] = lrelu(bn(S[n,o]-P[n,o] + max/min_k P[idx[n,k],o])) ----------------
__global__ void ecfinish_kernel(const float* __restrict__ Pt, const float* __restrict__ St,
                                const int* __restrict__ idx, int k, int O, int Np,
                                const float* __restrict__ g, const float* __restrict__ bb,
                                float* __restrict__ outp, long oStrideB) {
  int b = blockIdx.y;
  int n = blockIdx.x * blockDim.y + threadIdx.y;
  int o = threadIdx.x;
  const float* PtB = Pt + (long)b * Np * O;
  const float* StB = St + (long)b * Np * O;
  const int* ip = idx + ((long)b * Np + n) * k;
  float mx = -INFINITY, mn = INFINITY;
  for (int kk = 0; kk < k; ++kk) {
    float v = PtB[(long)ip[kk] * O + o];
    mx = fmaxf(mx, v); mn = fminf(mn, v);
  }
  float ctrP = PtB[(long)n * O + o];
  float ctrS = StB[(long)n * O + o];
  float gs = g[o] * BN_SCALE;
  float m = (gs >= 0.f) ? mx : mn;
  float h = (ctrS - ctrP + m) * gs + bb[o];
  outp[(long)b * oStrideB + (long)o * Np + n] = h >= 0.f ? h : 0.2f * h;
}

// ---------------- gemm_colmax: tile GEMM + lrelu(bn()) + max over n-tile -> partial[b][nt][o] ----------------
__global__ void gemm_colmax_kernel(const float* __restrict__ X, int xStrideB, int C, int Np,
                                   const float* __restrict__ W, int ldw, int O,
                                   const float* __restrict__ g, const float* __restrict__ bb,
                                   float* __restrict__ partial) {
  __shared__ float Wt[16][65];
  __shared__ float Xt[16][65];
  int b = blockIdx.z;
  int n0 = blockIdx.x * 64, o0 = blockIdx.y * 64;
  int tid = threadIdx.x;
  int to = tid % 16, tn = tid / 16;
  float acc[4][4] = {};
  for (int c0 = 0; c0 < C; c0 += 16) {
    for (int e = tid; e < 16 * 64; e += 256) {
      int oo = e / 16, kk = e % 16;
      int c = c0 + kk, o = o0 + oo;
      Wt[kk][oo] = (c < C && o < O) ? W[(long)o * ldw + c] : 0.f;
    }
    for (int e = tid; e < 16 * 64; e += 256) {
      int kk = e / 64, nn = e % 64;
      int c = c0 + kk, n = n0 + nn;
      Xt[kk][nn] = (c < C && n < Np) ? X[(long)b * xStrideB + (long)c * Np + n] : 0.f;
    }
    __syncthreads();
    for (int kk = 0; kk < 16; ++kk) {
      float xv[4], wv[4];
      for (int i = 0; i < 4; ++i) xv[i] = Xt[kk][tn + 16 * i];
      for (int j = 0; j < 4; ++j) wv[j] = Wt[kk][to + 16 * j];
      for (int i = 0; i < 4; ++i)
        for (int j = 0; j < 4; ++j) acc[i][j] = fmaf(xv[i], wv[j], acc[i][j]);
    }
    __syncthreads();
  }
  float vm[4];
  for (int j = 0; j < 4; ++j) {
    int o = o0 + to + 16 * j;
    float gs = g[o] * BN_SCALE, bo = bb[o];
    float m = -INFINITY;
    for (int i = 0; i < 4; ++i) {
      float h = acc[i][j] * gs + bo;
      h = h >= 0.f ? h : 0.2f * h;
      m = fmaxf(m, h);
    }
    vm[j] = m;
  }
  for (int j = 0; j < 4; ++j) Xt[tn][to + 16 * j] = vm[j];
  __syncthreads();
  for (int s = 8; s > 0; s >>= 1) {
    if (tn < s)
      for (int j = 0; j < 4; ++j)
        Xt[tn][to + 16 * j] = fmaxf(Xt[tn][to + 16 * j], Xt[tn + s][to + 16 * j]);
    __syncthreads();
  }
  if (tn == 0)
    for (int j = 0; j < 4; ++j) {
      int o = o0 + to + 16 * j;
      partial[((long)b * gridDim.x + blockIdx.x) * O + o] = Xt[0][to + 16 * j];
    }
}

// ---------------- colmax_finish: out[b][o] = max_t partial[b][t][o] ----------------
__global__ void colmax_finish_kernel(const float* __restrict__ partial, int NT, int O,
                                     float* __restrict__ outp) {
  int b = blockIdx.y;
  int o = blockIdx.x * 256 + threadIdx.x;
  if (o >= O) return;
  float m = -INFINITY;
  for (int t = 0; t < NT; ++t) m = fmaxf(m, partial[((long)b * NT + t) * O + o]);
  outp[(long)b * O + o] = m;
}

// ---------------- FPS: SINGLE WAVE per batch; dist in VGPRs (launch_bounds(64,1) to
// prevent spill); value-only butterfly + ballot/ffs argmax; no barriers ----------------
__global__ void __launch_bounds__(64, 1) fps_kernel(const float* __restrict__ xyz, int N, int M,
                                                    int* __restrict__ fpsIdx, float* __restrict__ node1) {
  #pragma clang fp contract(off)
  __shared__ float sx[2048], sy[2048], sz[2048];
  __shared__ int fidx[512];
  int b = blockIdx.x, lane = threadIdx.x;
  const float* xb = xyz + (long)b * 3 * N;
  for (int n = lane; n < N; n += 64) {
    sx[n] = xb[n]; sy[n] = xb[N + n]; sz[n] = xb[2 * N + n];
  }
  int base = lane * 32;
  float px[32], py[32], pz[32], dist[32];
  #pragma unroll
  for (int i = 0; i < 32; i += 4) {
    float4 a = *(const float4*)(xb + base + i);
    px[i] = a.x; px[i + 1] = a.y; px[i + 2] = a.z; px[i + 3] = a.w;
    float4 bb4 = *(const float4*)(xb + N + base + i);
    py[i] = bb4.x; py[i + 1] = bb4.y; py[i + 2] = bb4.z; py[i + 3] = bb4.w;
    float4 cc = *(const float4*)(xb + 2 * N + base + i);
    pz[i] = cc.x; pz[i + 1] = cc.y; pz[i + 2] = cc.z; pz[i + 3] = cc.w;
  }
  #pragma unroll
  for (int i = 0; i < 32; ++i) dist[i] = 1e10f;
  int last = 0;
  for (int it = 0; it < M; ++it) {
    if (lane == 0) fidx[it] = last;
    float lx = sx[last], ly = sy[last], lz = sz[last];  // same-address broadcast
    float best = -INFINITY; int bi = N;
    #pragma unroll
    for (int i = 0; i < 32; ++i) {
      float dx = px[i] - lx, dy = py[i] - ly, dz = pz[i] - lz;
      float dx2 = dx * dx, dy2 = dy * dy, dz2 = dz * dz;
      float d = (dx2 + dy2) + dz2;
      float dn = dist[i];
      if (d < dn) dn = d;
      dist[i] = dn;
      if (dn > best) { best = dn; bi = base + i; }  // ascending -> first max in lane kept
    }
    // value-only butterfly -> global max in all lanes
    float gmax = best;
    #pragma unroll
    for (int off = 32; off > 0; off >>= 1) {
      float ov = __shfl_xor(gmax, off);
      gmax = fmaxf(gmax, ov);
    }
    // first (smallest) lane holding gmax gives the first-occurrence argmax
    unsigned long long m = __ballot(best == gmax);
    int srcLane = (int)(__ffsll((long long)m) - 1);
    last = __shfl(bi, srcLane);
  }
  // flush fpsIdx + node1 from LDS
  for (int e = lane; e < M; e += 64) fpsIdx[(long)b * M + e] = fidx[e];
  for (int e = lane; e < 3 * M; e += 64) {
    int c = e / M, i = e % M;
    int src = fidx[i];
    float v = (c == 0) ? sx[src] : (c == 1) ? sy[src] : sz[src];
    node1[(long)b * 3 * M + e] = v;
  }
}

// ---------------- gather: out[b,c,i] = X[b,c,idx[b,i]] ----------------
__global__ void gather_kernel(const float* __restrict__ X, int xStrideB, int C, int N,
                              const int* __restrict__ idx, int M,
                              float* __restrict__ outp, int oStrideB, int B) {
  long t = (long)blockIdx.x * blockDim.x + threadIdx.x;
  long total = (long)B * C * M;
  if (t >= total) return;
  int i = (int)(t % M);
  int c = (int)((t / M) % C);
  int b = (int)(t / ((long)C * M));
  int src = idx[(long)b * M + i];
  outp[(long)b * oStrideB + (long)c * M + i] = X[(long)b * xStrideB + (long)c * N + src];
}

// ---------------- gathermax: out[b,c,i] = max_k X[b,c,idx[b,i,k]] ----------------
__global__ void gathermax_kernel(const float* __restrict__ X, int xStrideB, int C, int N,
                                 const int* __restrict__ idx, int k, int M,
                                 float* __restrict__ outp, int oStrideB, int B) {
  long t = (long)blockIdx.x * blockDim.x + threadIdx.x;
  long total = (long)B * C * M;
  if (t >= total) return;
  int i = (int)(t % M);
  int c = (int)((t / M) % C);
  int b = (int)(t / ((long)C * M));
  const int* ip = idx + ((long)b * M + i) * k;
  const float* xb = X + (long)b * xStrideB + (long)c * N;
  float best = -INFINITY;
  for (int kk = 0; kk < k; ++kk) best = fmaxf(best, xb[ip[kk]]);
  outp[(long)b * oStrideB + (long)c * M + i] = best;
}

// ---------------- head: v=[vf;vs] -> 3-layer MLP -> logits ----------------
__global__ void head_kernel(const float* __restrict__ vf, const float* __restrict__ vs,
                            const float* __restrict__ Wl1, const float* __restrict__ g6, const float* __restrict__ b6,
                            const float* __restrict__ Wl2, const float* __restrict__ bl2,
                            const float* __restrict__ g7, const float* __restrict__ b7,
                            const float* __restrict__ Wl3, const float* __restrict__ bl3,
                            float* __restrict__ logits) {
  __shared__ float v[2048];
  __shared__ float h1[512];
  __shared__ float h2[256];
  int b = blockIdx.x, tid = threadIdx.x;
  for (int c = tid; c < 1024; c += 256) {
    v[c]        = vf[(long)b * 1024 + c];
    v[1024 + c] = vs[(long)b * 1024 + c];
  }
  __syncthreads();
  for (int o = tid; o < 512; o += 256) {
    const float* wr = Wl1 + (long)o * 2048;
    float s = 0.f;
    for (int c = 0; c < 2048; c += 4) {
      float4 w4 = *(const float4*)(wr + c);
      s = fmaf(w4.x, v[c], s); s = fmaf(w4.y, v[c + 1], s);
      s = fmaf(w4.z, v[c + 2], s); s = fmaf(w4.w, v[c + 3], s);
    }
    float h = s * (g6[o] * BN_SCALE) + b6[o];
    h1[o] = h >= 0.f ? h : 0.2f * h;
  }
  __syncthreads();
  for (int o = tid; o < 256; o += 256) {
    const float* wr = Wl2 + (long)o * 512;
    float s = 0.f;
    for (int c = 0; c < 512; c += 4) {
      float4 w4 = *(const float4*)(wr + c);
      s = fmaf(w4.x, h1[c], s); s = fmaf(w4.y, h1[c + 1], s);
      s = fmaf(w4.z, h1[c + 2], s); s = fmaf(w4.w, h1[c + 3], s);
    }
    s += bl2[o];
    float h = s * (g7[o] * BN_SCALE) + b7[o];
    h2[o] = h >= 0.f ? h : 0.2f * h;
  }
  __syncthreads();
  if (tid < 40) {
    const float* wr = Wl3 + (long)tid * 256;
    float s = 0.f;
    for (int c = 0; c < 256; ++c) s = fmaf(wr[c], h2[c], s);
    logits[(long)b * 40 + tid] = s + bl3[tid];
  }
}

extern "C" void kernel_launch(void* const* d_in, const int* in_sizes, int n_in,
                              void* d_out, int out_size, void* d_ws, size_t ws_size,
                              hipStream_t stream) {
  const float* x   = (const float*)d_in[0];
  const float* W1  = (const float*)d_in[1];
  const float* g1  = (const float*)d_in[2];
  const float* b1  = (const float*)d_in[3];
  const float* W2  = (const float*)d_in[4];
  const float* g2  = (const float*)d_in[5];
  const float* b2  = (const float*)d_in[6];
  const float* W2m = (const float*)d_in[7];
  const float* g2m = (const float*)d_in[8];
  const float* b2m = (const float*)d_in[9];
  const float* W3  = (const float*)d_in[10];
  const float* g3  = (const float*)d_in[11];
  const float* b3  = (const float*)d_in[12];
  const float* W4  = (const float*)d_in[13];
  const float* g4  = (const float*)d_in[14];
  const float* b4  = (const float*)d_in[15];
  const float* W5  = (const float*)d_in[16];
  const float* g5  = (const float*)d_in[17];
  const float* b5  = (const float*)d_in[18];
  const float* Wl1 = (const float*)d_in[19];
  const float* g6  = (const float*)d_in[20];
  const float* b6  = (const float*)d_in[21];
  const float* Wl2 = (const float*)d_in[22];
  const float* bl2 = (const float*)d_in[23];
  const float* g7  = (const float*)d_in[24];
  const float* b7  = (const float*)d_in[25];
  const float* Wl3 = (const float*)d_in[26];
  const float* bl3 = (const float*)d_in[27];
  float* outF = (float*)d_out;

  const int B = 8, N = 2048, K = 20, M = 512, K2 = 10;

  float* ws   = (float*)d_ws;
  float* xt1  = ws;                              // (B,128,N)
  float* xm   = xt1 + (size_t)B * 128 * N;       // (B,256,M)
  float* xc   = xm  + (size_t)B * 256 * M;       // (B,512,M)
  float* Pt   = xc  + (size_t)B * 512 * M;       // (B,N,64)/(B,M,256)
  float* St   = Pt  + (size_t)B * N * 64;
  float* part = St  + (size_t)B * N * 64;        // (B,32,1024)
  float* vf   = part + (size_t)B * 32 * 1024;
  float* vs   = vf  + (size_t)B * 1024;
  float* sqa  = vs  + (size_t)B * 1024;
  float* sqb  = sqa + (size_t)B * N;
  float* sqn  = sqb + (size_t)B * N;
  int*   idxK = (int*)(sqn + (size_t)B * M);
  int*   fpsI = idxK + (size_t)B * N * K;

  float* logits = outF;        // (B,40)
  float* node1  = outF + 320;  // (B,3,M)

  dim3 t256(256);

  // ---- stage 1
  sqnorm_kernel<<<dim3((N + 255) / 256, B), t256, 0, stream>>>(x, 3 * N, 3, N, sqa);
  knn4_kernel<<<dim3(N / 4, B), t256, 0, stream>>>(x, 3 * N, x, 3 * N, sqa, sqa, 3, N, N, K, idxK);
  gemmT_kernel<<<dim3(N / 64, 1, B), t256, 0, stream>>>(x, 3 * N, 3, N, W1,     6, 64, Pt);
  gemmT_kernel<<<dim3(N / 64, 1, B), t256, 0, stream>>>(x, 3 * N, 3, N, W1 + 3, 6, 64, St);
  ecfinish_kernel<<<dim3(N / 4, B), dim3(64, 4), 0, stream>>>(Pt, St, idxK, K, 64, N, g1, b1, xt1, (long)128 * N);

  // FPS
  fps_kernel<<<dim3(B), dim3(64), 0, stream>>>(x, N, M, fpsI, node1);

  // ---- stage 2
  sqnorm_kernel<<<dim3((N + 255) / 256, B), t256, 0, stream>>>(xt1, 128 * N, 64, N, sqb);
  knn4_kernel<<<dim3(N / 4, B), t256, 0, stream>>>(xt1, 128 * N, xt1, 128 * N, sqb, sqb, 64, N, N, K, idxK);
  gemmT_kernel<<<dim3(N / 64, 1, B), t256, 0, stream>>>(xt1, 128 * N, 64, N, W2,      128, 64, Pt);
  gemmT_kernel<<<dim3(N / 64, 1, B), t256, 0, stream>>>(xt1, 128 * N, 64, N, W2 + 64, 128, 64, St);
  ecfinish_kernel<<<dim3(N / 4, B), dim3(64, 4), 0, stream>>>(Pt, St, idxK, K, 64, N, g2, b2,
                                                              xt1 + (size_t)64 * N, (long)128 * N);

  // ---- vf
  gemm_colmax_kernel<<<dim3(N / 64, 1024 / 64, B), t256, 0, stream>>>(xt1, 128 * N, 128, N, W2m, 128, 1024,
                                                                      g2m, b2m, part);
  colmax_finish_kernel<<<dim3(1024 / 256, B), t256, 0, stream>>>(part, N / 64, 1024, vf);

  // ---- nf1 gather
  gather_kernel<<<dim3((B * 128 * M + 255) / 256), t256, 0, stream>>>(xt1, 128 * N, 128, N, fpsI, M, xm, 256 * M, B);

  // ---- aggregate
  sqnorm_kernel<<<dim3((M + 255) / 256, B), t256, 0, stream>>>(node1, 3 * M, 3, M, sqn);
  knn4_kernel<<<dim3(M / 4, B), t256, 0, stream>>>(node1, 3 * M, x, 3 * N, sqn, sqa, 3, M, N, K, idxK);
  gathermax_kernel<<<dim3((B * 128 * M + 255) / 256), t256, 0, stream>>>(xt1, 128 * N, 128, N, idxK, K, M,
                                                                         xm + (size_t)128 * M, 256 * M, B);

  // ---- stage 3
  sqnorm_kernel<<<dim3((M + 255) / 256, B), t256, 0, stream>>>(xm, 256 * M, 256, M, sqb);
  knn4_kernel<<<dim3(M / 4, B), t256, 0, stream>>>(xm, 256 * M, xm, 256 * M, sqb, sqb, 256, M, M, K2, idxK);
  gemmT_kernel<<<dim3(M / 64, 256 / 64, B), t256, 0, stream>>>(xm, 256 * M, 256, M, W3,       512, 256, Pt);
  gemmT_kernel<<<dim3(M / 64, 256 / 64, B), t256, 0, stream>>>(xm, 256 * M, 256, M, W3 + 256, 512, 256, St);
  ecfinish_kernel<<<dim3(M, B), dim3(256, 1), 0, stream>>>(Pt, St, idxK, K2, 256, M, g3, b3, xc, (long)512 * M);

  // ---- stage 4
  sqnorm_kernel<<<dim3((M + 255) / 256, B), t256, 0, stream>>>(xc, 512 * M, 256, M, sqb);
  knn4_kernel<<<dim3(M / 4, B), t256, 0, stream>>>(xc, 512 * M, xc, 512 * M, sqb, sqb, 256, M, M, K2, idxK);
  gemmT_kernel<<<dim3(M / 64, 256 / 64, B), t256, 0, stream>>>(xc, 512 * M, 256, M, W4,       512, 256, Pt);
  gemmT_kernel<<<dim3(M / 64, 256 / 64, B), t256, 0, stream>>>(xc, 512 * M, 256, M, W4 + 256, 512, 256, St);
  ecfinish_kernel<<<dim3(M, B), dim3(256, 1), 0, stream>>>(Pt, St, idxK, K2, 256, M, g4, b4,
                                                           xc + (size_t)256 * M, (long)512 * M);

  // ---- vs
  gemm_colmax_kernel<<<dim3(M / 64, 1024 / 64, B), t256, 0, stream>>>(xc, 512 * M, 512, M, W5, 512, 1024,
                                                                      g5, b5, part);
  colmax_finish_kernel<<<dim3(1024 / 256, B), t256, 0, stream>>>(part, M / 64, 1024, vs);

  // ---- head
  head_kernel<<<dim3(B), t256, 0, stream>>>(vf, vs, Wl1, g6, b6, Wl2, bl2, g7, b7, Wl3, bl3, logits);
}